// Round 2
// baseline (262.567 us; speedup 1.0000x reference)
//
#include <hip/hip_runtime.h>
#include <hip/hip_cooperative_groups.h>

namespace cg = cooperative_groups;

// GIoU loss, N=4M boxes, [N,4] f32 -> one float4 per box (16B/lane coalesced).
// 128 MB read/call.
// R2-R4: pinned at 42.5us = 3.0 TB/s via the IF$-retention read path.
// R6: nontemporal loads -> main kernel <40.5us (out of top-5), ~34us by
//     subtraction. Harness fill shows 6.6 TB/s write is achievable.
// R7: __launch_bounds__(256,4), 16 nt loads in flight -> 135.5us.
// R8: 32 waves/CU, 8 loads in flight -> 137.6us (no change). Occupancy was
//     never the limiter (~40KB/CU in flight vs ~10KB needed at 900cy lat).
// R9 (this round): fuse main+finalize into ONE persistent cooperative kernel.
//     Removes the finalize dispatch + inter-kernel gap, kills block
//     launch/retire churn (last structural theory for <6TB/s reads), and
//     makes the kernel big enough to appear in top-5 -> direct BW readout.

#define TPB 256

typedef float vfloat4 __attribute__((ext_vector_type(4)));

__device__ __forceinline__ vfloat4 nt_load(const vfloat4* p) {
    return __builtin_nontemporal_load(p);
}

__device__ __forceinline__ float giou_term(vfloat4 p, vfloat4 t) {
    // box = {x1,y1,x2,y2}
    float area_p = (p.z - p.x) * (p.w - p.y);
    float area_t = (t.z - t.x) * (t.w - t.y);
    float iw = fmaxf(fminf(p.z, t.z) - fmaxf(p.x, t.x), 0.0f);
    float ih = fmaxf(fminf(p.w, t.w) - fmaxf(p.y, t.y), 0.0f);
    float inter = iw * ih;
    float uni   = area_p + area_t - inter;
    float iou   = inter / uni;
    float cw = fmaxf(p.z, t.z) - fminf(p.x, t.x);
    float ch = fmaxf(p.w, t.w) - fminf(p.y, t.y);
    float area_c = cw * ch;
    return 1.0f - (iou - (area_c - uni) / area_c);
}

__global__ __launch_bounds__(TPB, 8) void giou_fused_kernel(
        const vfloat4* __restrict__ pred,
        const vfloat4* __restrict__ targ,
        float* __restrict__ partials,
        float* __restrict__ out,
        int n, double inv_n) {
    const int S = (int)gridDim.x * TPB;
    int i = (int)blockIdx.x * TPB + (int)threadIdx.x;
    float sum = 0.0f;

    // Main grid-stride loop, batched so 8 nt dwordx4 loads are in flight.
    while (i + 3 * S < n) {
        vfloat4 p0 = nt_load(&pred[i]);
        vfloat4 p1 = nt_load(&pred[i + S]);
        vfloat4 p2 = nt_load(&pred[i + 2 * S]);
        vfloat4 p3 = nt_load(&pred[i + 3 * S]);
        vfloat4 t0 = nt_load(&targ[i]);
        vfloat4 t1 = nt_load(&targ[i + S]);
        vfloat4 t2 = nt_load(&targ[i + 2 * S]);
        vfloat4 t3 = nt_load(&targ[i + 3 * S]);
        sum += giou_term(p0, t0);
        sum += giou_term(p1, t1);
        sum += giou_term(p2, t2);
        sum += giou_term(p3, t3);
        i += 4 * S;
    }
    for (; i < n; i += S)
        sum += giou_term(nt_load(&pred[i]), nt_load(&targ[i]));

    // wave reduce (wave = 64)
    #pragma unroll
    for (int off = 32; off > 0; off >>= 1)
        sum += __shfl_down(sum, off, 64);

    __shared__ float wave_sums[TPB / 64];
    const int lane = threadIdx.x & 63;
    const int wid  = threadIdx.x >> 6;
    if (lane == 0) wave_sums[wid] = sum;
    __syncthreads();
    if (threadIdx.x == 0) {
        partials[blockIdx.x] = wave_sums[0] + wave_sums[1]
                             + wave_sums[2] + wave_sums[3];
    }

    cg::this_grid().sync();

    // Block 0 finalizes: deterministic double-precision reduce of partials.
    if (blockIdx.x == 0) {
        double s = 0.0;
        for (int j = threadIdx.x; j < (int)gridDim.x; j += TPB)
            s += (double)partials[j];
        #pragma unroll
        for (int off = 32; off > 0; off >>= 1)
            s += __shfl_down(s, off, 64);
        __shared__ double dsum[TPB / 64];
        if (lane == 0) dsum[wid] = s;
        __syncthreads();
        if (threadIdx.x == 0) {
            *out = (float)((dsum[0] + dsum[1] + dsum[2] + dsum[3]) * inv_n);
        }
    }
}

extern "C" void kernel_launch(void* const* d_in, const int* in_sizes, int n_in,
                              void* d_out, int out_size, void* d_ws, size_t ws_size,
                              hipStream_t stream) {
    const vfloat4* pred = (const vfloat4*)d_in[0];
    const vfloat4* targ = (const vfloat4*)d_in[1];
    float* out      = (float*)d_out;
    float* partials = (float*)d_ws;          // grid floats, all written
    int n = in_sizes[0] / 4;                 // 4,000,000 boxes
    double inv_n = 1.0 / (double)n;

    // Cooperative launch: grid must be fully co-resident. Query once, cache.
    static int max_blocks = 0;
    if (max_blocks == 0) {
        int per_cu = 0;
        (void)hipOccupancyMaxActiveBlocksPerMultiprocessor(
            &per_cu, (const void*)giou_fused_kernel, TPB, 0);
        int num_cu = 0;
        (void)hipDeviceGetAttribute(&num_cu,
            hipDeviceAttributeMultiprocessorCount, 0);
        if (per_cu <= 0) per_cu = 4;         // conservative fallback
        if (num_cu <= 0) num_cu = 256;
        max_blocks = per_cu * num_cu;
    }
    int grid = max_blocks < 2048 ? max_blocks : 2048;

    void* args[] = { (void*)&pred, (void*)&targ, (void*)&partials,
                     (void*)&out, (void*)&n, (void*)&inv_n };
    (void)hipLaunchCooperativeKernel((const void*)giou_fused_kernel,
                                     dim3(grid), dim3(TPB), args, 0, stream);
}

// Round 3
// 230.666 us; speedup vs baseline: 1.1383x; 1.1383x over previous
//
#include <hip/hip_runtime.h>

// GIoU loss, N=4M boxes, [N,4] f32 -> one float4 per box (16B/lane coalesced).
// 128 MB read/call.
// R2-R4: pinned at 42.5us = 3.0 TB/s via the IF$-retention read path.
// R6: nontemporal loads -> main kernel <40.5us (out of top-5), ~34us by
//     subtraction. Harness fill shows 6.6 TB/s write is achievable.
// R7: __launch_bounds__(256,4), 16 nt loads in flight -> 135.5us. BEST.
// R8: 32 waves/CU, 8 loads in flight -> 137.6us (no change). Occupancy is
//     not the limiter.
// R9: cooperative fused kernel -> 255us kernel time. cg::this_grid().sync()
//     on 2048 blocks burns ~200us spinning across 8 non-coherent XCD L2s
//     (VALUBusy 2.8%, 32 VGPR). NEVER grid-sync a one-shot reduction.
//     Useful datum: FETCH_SIZE=65MB for 128MB of reads -> ~half the input
//     survives in L3 across iterations.
// R10 (this round): R7 structure exactly + last-block-done finalize fuse:
//     partial -> threadfence -> atomicAdd ticket; last block reduces 1954
//     partials in double and writes out. Counter zeroed via 4B memsetAsync.
//     Removes the finalize dispatch + gap. Predict 137.6 -> ~124-130.

#define TPB         256
#define PER_THREAD  8
#define CHUNK       (TPB * PER_THREAD)   // 2048 boxes per block

typedef float vfloat4 __attribute__((ext_vector_type(4)));

__device__ __forceinline__ vfloat4 nt_load(const vfloat4* p) {
    return __builtin_nontemporal_load(p);
}

__device__ __forceinline__ float giou_term(vfloat4 p, vfloat4 t) {
    // box = {x1,y1,x2,y2}
    float area_p = (p.z - p.x) * (p.w - p.y);
    float area_t = (t.z - t.x) * (t.w - t.y);
    float iw = fmaxf(fminf(p.z, t.z) - fmaxf(p.x, t.x), 0.0f);
    float ih = fmaxf(fminf(p.w, t.w) - fmaxf(p.y, t.y), 0.0f);
    float inter = iw * ih;
    float uni   = area_p + area_t - inter;
    float iou   = inter / uni;
    float cw = fmaxf(p.z, t.z) - fminf(p.x, t.x);
    float ch = fmaxf(p.w, t.w) - fminf(p.y, t.y);
    float area_c = cw * ch;
    return 1.0f - (iou - (area_c - uni) / area_c);
}

__global__ __launch_bounds__(TPB, 4) void giou_fused_kernel(
        const vfloat4* __restrict__ pred,
        const vfloat4* __restrict__ targ,
        float* __restrict__ partials,
        unsigned int* __restrict__ counter,
        float* __restrict__ out,
        int n, int nblocks, double inv_n) {
    const int base = blockIdx.x * CHUNK;
    const int i0   = base + threadIdx.x;
    float sum = 0.0f;

    if (base + CHUNK <= n) {
        // 16 independent nt dwordx4 loads, all issued before any consumption.
        // launch_bounds(256,4) -> <=128 VGPR so all 16 stay in flight.
        vfloat4 p[PER_THREAD], t[PER_THREAD];
        #pragma unroll
        for (int k = 0; k < PER_THREAD; ++k) p[k] = nt_load(&pred[i0 + k * TPB]);
        #pragma unroll
        for (int k = 0; k < PER_THREAD; ++k) t[k] = nt_load(&targ[i0 + k * TPB]);
        #pragma unroll
        for (int k = 0; k < PER_THREAD; ++k) sum += giou_term(p[k], t[k]);
    } else {
        #pragma unroll
        for (int k = 0; k < PER_THREAD; ++k) {
            int i = i0 + k * TPB;
            if (i < n) sum += giou_term(nt_load(&pred[i]), nt_load(&targ[i]));
        }
    }

    // wave reduce (wave = 64)
    #pragma unroll
    for (int off = 32; off > 0; off >>= 1)
        sum += __shfl_down(sum, off, 64);

    __shared__ float wave_sums[TPB / 64];
    __shared__ int is_last;
    const int lane = threadIdx.x & 63;
    const int wid  = threadIdx.x >> 6;
    if (lane == 0) wave_sums[wid] = sum;
    __syncthreads();

    if (threadIdx.x == 0) {
        partials[blockIdx.x] = wave_sums[0] + wave_sums[1]
                             + wave_sums[2] + wave_sums[3];
        __threadfence();                       // release partial (device scope)
        unsigned int old = atomicAdd(counter, 1u);   // device-scope by default
        is_last = (old == (unsigned int)(nblocks - 1));
    }
    __syncthreads();

    // Exactly one block (the last to finish) reduces all partials.
    if (is_last) {
        __threadfence();                       // acquire: invalidate L1, see all partials
        double s = 0.0;
        for (int j = threadIdx.x; j < nblocks; j += TPB)
            s += (double)partials[j];
        #pragma unroll
        for (int off = 32; off > 0; off >>= 1)
            s += __shfl_down(s, off, 64);
        __shared__ double dsum[TPB / 64];
        if (lane == 0) dsum[wid] = s;
        __syncthreads();
        if (threadIdx.x == 0) {
            *out = (float)((dsum[0] + dsum[1] + dsum[2] + dsum[3]) * inv_n);
        }
    }
}

extern "C" void kernel_launch(void* const* d_in, const int* in_sizes, int n_in,
                              void* d_out, int out_size, void* d_ws, size_t ws_size,
                              hipStream_t stream) {
    const vfloat4* pred = (const vfloat4*)d_in[0];
    const vfloat4* targ = (const vfloat4*)d_in[1];
    float* out = (float*)d_out;

    // ws layout: [0..3] ticket counter, [256..] per-block partials
    unsigned int* counter = (unsigned int*)d_ws;
    float* partials = (float*)((char*)d_ws + 256);

    int n = in_sizes[0] / 4;                 // 4,000,000 boxes
    int nblocks = (n + CHUNK - 1) / CHUNK;   // 1954

    (void)hipMemsetAsync(d_ws, 0, 4, stream);     // zero the ticket counter
    giou_fused_kernel<<<nblocks, TPB, 0, stream>>>(pred, targ, partials,
                                                   counter, out, n, nblocks,
                                                   1.0 / (double)n);
}

// Round 4
// 135.308 us; speedup vs baseline: 1.9405x; 1.7047x over previous
//
#include <hip/hip_runtime.h>

// GIoU loss, N=4M boxes, [N,4] f32 -> one float4 per box (16B/lane coalesced).
// 128 MB read/call.
// R2-R4: pinned at 42.5us = 3.0 TB/s via the IF$-retention read path.
// R6: nontemporal loads -> main kernel <40.5us (out of top-5), ~34us by
//     subtraction. Harness fill shows 6.6 TB/s write is achievable.
// R7: __launch_bounds__(256,4), 16 nt loads "in flight" -> 135.5us. BEST.
// R8: 32 waves/CU variant -> no change. Occupancy not the limiter.
// R9: cooperative fuse -> 255us. Grid-sync spin across 8 non-coherent XCDs.
// R10: last-block fuse -> 120us kernel. threadfence+atomic ticket on one
//      line serializes 1954 block retirements cross-XCD (~85us). ALSO
//      revealed VGPR_Count=36: launch_bounds only CAPS regs; the compiler's
//      occupancy heuristic still sinks each load to its use -> the 16-deep
//      batch never existed. MLP ~2/wave explains the 3.8 TB/s plateau.
// R11 (this round): revert to two-kernel R7 structure; interleave (p,t)
//      load pairs and pin with __builtin_amdgcn_sched_barrier(0) so all 16
//      nt loads are issued before any compute (forces ~100 VGPR, term k
//      waits vmcnt(14-2k)). Predict main 34 -> ~23us, dur_us -> ~122-127.

#define TPB         256
#define PER_THREAD  8
#define CHUNK       (TPB * PER_THREAD)   // 2048 boxes per block

typedef float vfloat4 __attribute__((ext_vector_type(4)));

__device__ __forceinline__ vfloat4 nt_load(const vfloat4* p) {
    return __builtin_nontemporal_load(p);
}

__device__ __forceinline__ float giou_term(vfloat4 p, vfloat4 t) {
    // box = {x1,y1,x2,y2}
    float area_p = (p.z - p.x) * (p.w - p.y);
    float area_t = (t.z - t.x) * (t.w - t.y);
    float iw = fmaxf(fminf(p.z, t.z) - fmaxf(p.x, t.x), 0.0f);
    float ih = fmaxf(fminf(p.w, t.w) - fmaxf(p.y, t.y), 0.0f);
    float inter = iw * ih;
    float uni   = area_p + area_t - inter;
    float iou   = inter / uni;
    float cw = fmaxf(p.z, t.z) - fminf(p.x, t.x);
    float ch = fmaxf(p.w, t.w) - fminf(p.y, t.y);
    float area_c = cw * ch;
    return 1.0f - (iou - (area_c - uni) / area_c);
}

__global__ __launch_bounds__(TPB, 4) void giou_main_kernel(
        const vfloat4* __restrict__ pred,
        const vfloat4* __restrict__ targ,
        float* __restrict__ partials,
        int n) {
    const int base = blockIdx.x * CHUNK;
    const int i0   = base + threadIdx.x;
    float sum = 0.0f;

    if (base + CHUNK <= n) {
        vfloat4 p[PER_THREAD], t[PER_THREAD];
        // Issue all 16 nt dwordx4 loads, interleaved (p0,t0,p1,t1,...) so
        // consumption of term k only waits vmcnt(14-2k).
        #pragma unroll
        for (int k = 0; k < PER_THREAD; ++k) {
            p[k] = nt_load(&pred[i0 + k * TPB]);
            t[k] = nt_load(&targ[i0 + k * TPB]);
        }
        // Pin the schedule: no load may sink past this point. Forces all 16
        // results live -> compiler must allocate the batch and issue
        // back-to-back (defeats its 36-VGPR occupancy heuristic, see R10).
        __builtin_amdgcn_sched_barrier(0);
        #pragma unroll
        for (int k = 0; k < PER_THREAD; ++k) sum += giou_term(p[k], t[k]);
    } else {
        #pragma unroll
        for (int k = 0; k < PER_THREAD; ++k) {
            int i = i0 + k * TPB;
            if (i < n) sum += giou_term(nt_load(&pred[i]), nt_load(&targ[i]));
        }
    }

    // wave reduce (wave = 64)
    #pragma unroll
    for (int off = 32; off > 0; off >>= 1)
        sum += __shfl_down(sum, off, 64);

    __shared__ float wave_sums[TPB / 64];
    const int lane = threadIdx.x & 63;
    const int wid  = threadIdx.x >> 6;
    if (lane == 0) wave_sums[wid] = sum;
    __syncthreads();
    if (threadIdx.x == 0) {
        partials[blockIdx.x] = wave_sums[0] + wave_sums[1]
                             + wave_sums[2] + wave_sums[3];
    }
}

__global__ __launch_bounds__(TPB) void giou_finalize_kernel(
        const float* __restrict__ partials, int nblocks,
        float* __restrict__ out, double inv_n) {
    double s = 0.0;
    for (int i = threadIdx.x; i < nblocks; i += TPB)
        s += (double)partials[i];
    #pragma unroll
    for (int off = 32; off > 0; off >>= 1)
        s += __shfl_down(s, off, 64);
    __shared__ double wave_sums[TPB / 64];
    int lane = threadIdx.x & 63;
    int wid  = threadIdx.x >> 6;
    if (lane == 0) wave_sums[wid] = s;
    __syncthreads();
    if (threadIdx.x == 0) {
        double tot = wave_sums[0] + wave_sums[1] + wave_sums[2] + wave_sums[3];
        *out = (float)(tot * inv_n);
    }
}

extern "C" void kernel_launch(void* const* d_in, const int* in_sizes, int n_in,
                              void* d_out, int out_size, void* d_ws, size_t ws_size,
                              hipStream_t stream) {
    const vfloat4* pred = (const vfloat4*)d_in[0];
    const vfloat4* targ = (const vfloat4*)d_in[1];
    float* out      = (float*)d_out;
    float* partials = (float*)d_ws;          // nblocks floats, all written
    int n = in_sizes[0] / 4;                 // 4,000,000 boxes
    int nblocks = (n + CHUNK - 1) / CHUNK;   // 1954

    giou_main_kernel<<<nblocks, TPB, 0, stream>>>(pred, targ, partials, n);
    giou_finalize_kernel<<<1, TPB, 0, stream>>>(partials, nblocks, out,
                                                1.0 / (double)n);
}